// Round 1
// baseline (265.212 us; speedup 1.0000x reference)
//
#include <hip/hip_runtime.h>
#include <hip/hip_bf16.h>

#define BB 2
#define CC 128
#define HH 48
#define WW 48
#define NN (HH*WW)      // 2304
#define NBIN 26         // 25 bins + spill bin (only ever receives 0.0)
#define QT 16           // queries per block
#define MT 64           // m per iteration
#define MSPLIT 2        // split m-range across blocks
#define NTILES (NN/QT)  // 144

typedef __bf16 bf16x8 __attribute__((ext_vector_type(8)));
typedef float  f32x4  __attribute__((ext_vector_type(4)));
typedef unsigned short u16;

static __device__ __forceinline__ u16 f2bf(float x) {
    __hip_bfloat16 h = __float2bfloat16(x);
    return __builtin_bit_cast(u16, h);
}

// img1 (B,C,H,W) -> Qt[b][n][c] bf16   (coalesced read, scattered write; L2 absorbs)
__global__ void k_transpose(const float* __restrict__ img1, u16* __restrict__ Qt) {
    int idx = blockIdx.x * 256 + threadIdx.x;   // < BB*CC*NN
    int n = idx % NN;
    int c = (idx / NN) % CC;
    int b = idx / (NN * CC);
    Qt[((size_t)(b * NN + n)) * CC + c] = f2bf(img1[idx]);
}

// bilinear grid_sample (align_corners=False, zero pad) -> Dt[b][m][c] bf16
__global__ void k_gridsample(const float* __restrict__ img2, const float* __restrict__ grid,
                             u16* __restrict__ Dt) {
    int bm = blockIdx.x;          // b*NN + m
    int b  = bm / NN;
    int c  = threadIdx.x;         // 0..127
    float gx = grid[bm * 2 + 0];
    float gy = grid[bm * 2 + 1];
    float ix = ((gx + 1.0f) * (float)WW - 1.0f) * 0.5f;
    float iy = ((gy + 1.0f) * (float)HH - 1.0f) * 0.5f;
    float x0f = floorf(ix), y0f = floorf(iy);
    float wx1 = ix - x0f, wy1 = iy - y0f;
    float wx0 = 1.0f - wx1, wy0 = 1.0f - wy1;
    int x0 = (int)x0f, y0 = (int)y0f;
    const float* im = img2 + (size_t)b * CC * NN + (size_t)c * NN;
    bool xv0 = (x0 >= 0) && (x0 < WW);
    bool xv1 = (x0 + 1 >= 0) && (x0 + 1 < WW);
    bool yv0 = (y0 >= 0) && (y0 < HH);
    bool yv1 = (y0 + 1 >= 0) && (y0 + 1 < HH);
    float acc = 0.0f;
    if (xv0 && yv0) acc += im[y0 * WW + x0]           * wx0 * wy0;
    if (xv1 && yv0) acc += im[y0 * WW + x0 + 1]       * wx1 * wy0;
    if (xv0 && yv1) acc += im[(y0 + 1) * WW + x0]     * wx0 * wy1;
    if (xv1 && yv1) acc += im[(y0 + 1) * WW + x0 + 1] * wx1 * wy1;
    Dt[(size_t)bm * CC + c] = f2bf(acc);
}

// main: S tile via MFMA, fused soft-histogram epilogue into LDS hists
__global__ __launch_bounds__(256)
void k_main(const u16* __restrict__ Qt, const u16* __restrict__ Dt,
            float* __restrict__ Hall, float* __restrict__ Hpos) {
    __shared__ u16  Qs[QT * 136];   // +8 bf16 pad per row -> 2-way (free) bank aliasing
    __shared__ u16  Ds[MT * 136];
    __shared__ float h_all[QT * NBIN];
    __shared__ float h_pos[QT * NBIN];

    int tid  = threadIdx.x;
    int bidx = blockIdx.x;
    int b     = bidx / (NTILES * MSPLIT);
    int rem   = bidx % (NTILES * MSPLIT);
    int ntile = rem >> 1;
    int mhalf = rem & 1;
    int n0 = ntile * QT;

    for (int i = tid; i < QT * NBIN; i += 256) { h_all[i] = 0.0f; h_pos[i] = 0.0f; }
    {   // load Q tile: 16 rows x 128 bf16 (16 uint4 per row), one uint4 per thread
        int row = tid >> 4, col = tid & 15;
        const uint4* src = reinterpret_cast<const uint4*>(
            Qt + ((size_t)(b * NN + n0 + row)) * CC + col * 8);
        *reinterpret_cast<uint4*>(&Qs[row * 136 + col * 8]) = *src;
    }
    int lane = tid & 63;
    int wave = tid >> 6;
    int quad = lane >> 4;
    int l15  = lane & 15;
    int rn[4], cn[4];
    #pragma unroll
    for (int i = 0; i < 4; ++i) {
        int n = n0 + quad * 4 + i;    // query row this lane+reg holds in C layout
        rn[i] = n / WW; cn[i] = n % WW;
    }

    int mstart = mhalf * (NN / MSPLIT);
    for (int it = 0; it < (NN / MSPLIT) / MT; ++it) {
        int m0 = mstart + it * MT;
        __syncthreads();   // previous iteration's frag reads done before overwrite
        #pragma unroll
        for (int k = 0; k < 4; ++k) {   // 64 rows x 16 uint4 = 1024 loads / 256 thr
            int idx = tid + k * 256;
            int row = idx >> 4, col = idx & 15;
            const uint4* src = reinterpret_cast<const uint4*>(
                Dt + ((size_t)(b * NN + m0 + row)) * CC + col * 8);
            *reinterpret_cast<uint4*>(&Ds[row * 136 + col * 8]) = *src;
        }
        __syncthreads();

        f32x4 acc = {0.f, 0.f, 0.f, 0.f};
        #pragma unroll
        for (int kc = 0; kc < 4; ++kc) {  // K = 128 = 4 x 32
            bf16x8 av = *reinterpret_cast<const bf16x8*>(&Qs[l15 * 136 + kc * 32 + quad * 8]);
            bf16x8 bv = *reinterpret_cast<const bf16x8*>(&Ds[(wave * 16 + l15) * 136 + kc * 32 + quad * 8]);
            acc = __builtin_amdgcn_mfma_f32_16x16x32_bf16(av, bv, acc, 0, 0, 0);
        }

        // epilogue: lane holds S[q = quad*4+i][m = m0 + wave*16 + l15]
        int m  = m0 + wave * 16 + l15;
        int rm = m / WW, cm = m % WW;
        #pragma unroll
        for (int i = 0; i < 4; ++i) {
            int   q  = quad * 4 + i;
            float s  = acc[i];
            float tq = 12.0f - 12.0f * s;          // t = 12(1-s): bin coordinate
            tq = fminf(fmaxf(tq, 0.0f), 24.0f);    // edge bins saturate (matches clamp in ref)
            float cf = floorf(tq);
            float f  = tq - cf;
            int   c0 = (int)cf;                    // c0 in [0,24]; c0+1 <= 25 (spill bin gets f=0 when c0==24? no: only c0==24 when tq==24 -> f==0)
            float* hb = &h_all[q * NBIN + c0];
            atomicAdd(hb,     1.0f - f);
            atomicAdd(hb + 1, f);
            int dr = rn[i] - rm, dc = cn[i] - cm;
            if (dr * dr <= 16 && dc * dc <= 16) {  // |dr|<=4 && |dc|<=4 : label
                float* pb = &h_pos[q * NBIN + c0];
                atomicAdd(pb,     1.0f - f);
                atomicAdd(pb + 1, f);
            }
        }
    }
    __syncthreads();
    // flush partial hists (two m-halves share a query tile -> global atomics)
    for (int i = tid; i < QT * NBIN; i += 256) {
        int q = i / NBIN, c = i % NBIN;
        size_t g = ((size_t)(b * NN + n0 + q)) * NBIN + c;
        atomicAdd(&Hall[g], h_all[i]);
        atomicAdd(&Hpos[g], h_pos[i]);
    }
}

// AP from histograms + reliability + mean -> scalar
__global__ void k_finalize(const float* __restrict__ Hall, const float* __restrict__ Hpos,
                           const float* __restrict__ rel, float* __restrict__ out) {
    int gid = blockIdx.x * 256 + threadIdx.x;   // 0..4607 (= B*N exactly)
    const float* ha = Hall + (size_t)gid * NBIN;
    const float* hp = Hpos + (size_t)gid * NBIN;
    float cumr = 0.f, cumn = 0.f, apn = 0.f, totr = 0.f;
    #pragma unroll
    for (int c2 = 0; c2 < 25; ++c2) {
        float r = hp[c2], a = ha[c2];
        cumr += r; cumn += a;
        apn  += (cumr / (1e-16f + cumn)) * r;
        totr += r;
    }
    float ap = apn / totr;                       // totr >= 1 (self-match always positive)
    float rl = rel[gid];
    float loss = 1.0f - (ap * rl + 0.5f * (1.0f - rl));

    for (int off = 32; off > 0; off >>= 1) loss += __shfl_down(loss, off, 64);
    __shared__ float wsum[4];
    int ln = threadIdx.x & 63, wv = threadIdx.x >> 6;
    if (ln == 0) wsum[wv] = loss;
    __syncthreads();
    if (threadIdx.x == 0) {
        float t = wsum[0] + wsum[1] + wsum[2] + wsum[3];
        atomicAdd(out, t * (1.0f / (float)(BB * NN)));
    }
}

extern "C" void kernel_launch(void* const* d_in, const int* in_sizes, int n_in,
                              void* d_out, int out_size, void* d_ws, size_t ws_size,
                              hipStream_t stream) {
    const float* img1 = (const float*)d_in[0];   // (B,C,H,W)
    const float* img2 = (const float*)d_in[1];   // (B,C,H,W)
    const float* rel  = (const float*)d_in[2];   // (B,1,H,W)
    const float* grid = (const float*)d_in[3];   // (B,H,W,2)

    char* ws = (char*)d_ws;
    const size_t qt_bytes   = (size_t)BB * NN * CC * sizeof(u16);  // 1.18 MB each
    const size_t hist_bytes = (size_t)BB * NN * NBIN * sizeof(float);
    u16*   Qt   = (u16*)ws;
    u16*   Dt   = (u16*)(ws + qt_bytes);
    float* Hall = (float*)(ws + 2 * qt_bytes);
    float* Hpos = (float*)(ws + 2 * qt_bytes + hist_bytes);

    hipMemsetAsync(d_out, 0, sizeof(float), stream);
    hipMemsetAsync(Hall, 0, 2 * hist_bytes, stream);   // Hall+Hpos contiguous

    k_transpose <<<(BB * CC * NN) / 256, 256, 0, stream>>>(img1, Qt);
    k_gridsample<<<BB * NN, 128, 0, stream>>>(img2, grid, Dt);
    k_main      <<<BB * NTILES * MSPLIT, 256, 0, stream>>>(Qt, Dt, Hall, Hpos);
    k_finalize  <<<(BB * NN) / 256, 256, 0, stream>>>(Hall, Hpos, rel, (float*)d_out);
}

// Round 2
// 111.215 us; speedup vs baseline: 2.3847x; 2.3847x over previous
//
#include <hip/hip_runtime.h>
#include <hip/hip_bf16.h>

#define BB 2
#define CC 128
#define HH 48
#define WW 48
#define NN (HH*WW)        // 2304
#define NBIN 26           // 25 bins + spill (only ever gets +0.0)
#define QT 16             // queries per block
#define MT 64             // m per iteration
#define MSPLIT 4          // split m-range across blocks -> 1152 blocks
#define NTILES (NN/QT)    // 144
#define ITERS (NN/MSPLIT/MT)  // 9
#define HSTRIDE 27        // private hist stride (odd -> banks spread)

typedef __bf16 bf16x8 __attribute__((ext_vector_type(8)));
typedef float  f32x4  __attribute__((ext_vector_type(4)));
typedef unsigned short u16;

static __device__ __forceinline__ u16 f2bf(float x) {
    __hip_bfloat16 h = __float2bfloat16(x);
    return __builtin_bit_cast(u16, h);
}

// img1 (B,C,H,W) -> Qt[b][n][c] bf16
__global__ void k_transpose(const float* __restrict__ img1, u16* __restrict__ Qt) {
    int idx = blockIdx.x * 256 + threadIdx.x;
    int n = idx % NN;
    int c = (idx / NN) % CC;
    int b = idx / (NN * CC);
    Qt[((size_t)(b * NN + n)) * CC + c] = f2bf(img1[idx]);
}

// bilinear grid_sample -> Dt[b][m][c] bf16.  m-parallel, c-chunked:
// each 9.2KB (H,W) plane is L1-resident while 256 threads gather from it.
#define CSPLIT 8
#define CCHUNK (CC/CSPLIT)   // 16 channels per block
__global__ __launch_bounds__(256)
void k_gridsample(const float* __restrict__ img2, const float* __restrict__ grid,
                  u16* __restrict__ Dt) {
    int blk = blockIdx.x;
    int bm  = (blk >> 3) * 256 + threadIdx.x;   // b*NN + m  (18*256 = 4608)
    int cc0 = (blk & 7) * CCHUNK;
    int b   = bm / NN;
    float gx = grid[bm * 2 + 0];
    float gy = grid[bm * 2 + 1];
    float ix = ((gx + 1.0f) * (float)WW - 1.0f) * 0.5f;
    float iy = ((gy + 1.0f) * (float)HH - 1.0f) * 0.5f;
    float x0f = floorf(ix), y0f = floorf(iy);
    float wx1 = ix - x0f, wy1 = iy - y0f;
    float wx0 = 1.0f - wx1, wy0 = 1.0f - wy1;
    int x0 = (int)x0f, y0 = (int)y0f;
    bool xv0 = (x0 >= 0) && (x0 < WW);
    bool xv1 = (x0 + 1 >= 0) && (x0 + 1 < WW);
    bool yv0 = (y0 >= 0) && (y0 < HH);
    bool yv1 = (y0 + 1 >= 0) && (y0 + 1 < HH);
    int x0c = min(max(x0, 0), WW - 1), x1c = min(max(x0 + 1, 0), WW - 1);
    int y0c = min(max(y0, 0), HH - 1), y1c = min(max(y0 + 1, 0), HH - 1);
    float w00 = (xv0 && yv0) ? wx0 * wy0 : 0.0f;
    float w01 = (xv1 && yv0) ? wx1 * wy0 : 0.0f;
    float w10 = (xv0 && yv1) ? wx0 * wy1 : 0.0f;
    float w11 = (xv1 && yv1) ? wx1 * wy1 : 0.0f;
    int p00 = y0c * WW + x0c, p01 = y0c * WW + x1c;
    int p10 = y1c * WW + x0c, p11 = y1c * WW + x1c;
    const float* im = img2 + (size_t)b * CC * NN + (size_t)cc0 * NN;
    u16 tmp[CCHUNK];
    #pragma unroll
    for (int c = 0; c < CCHUNK; ++c) {
        const float* pl = im + (size_t)c * NN;
        float v = pl[p00] * w00 + pl[p01] * w01 + pl[p10] * w10 + pl[p11] * w11;
        tmp[c] = f2bf(v);
    }
    uint4* dst = reinterpret_cast<uint4*>(Dt + (size_t)bm * CC + cc0);
    dst[0] = *reinterpret_cast<uint4*>(&tmp[0]);
    dst[1] = *reinterpret_cast<uint4*>(&tmp[8]);
}

// main: transposed MFMA (C[m][q]) so each lane owns ONE query; per-thread
// private LDS histograms (no atomics); sparse LDS atomics for positives only.
__global__ __launch_bounds__(256)
void k_main(const u16* __restrict__ Qt, const u16* __restrict__ Dt,
            float* __restrict__ Hall, float* __restrict__ Hpos) {
    __shared__ u16  Qs[QT * 136];
    __shared__ u16  Ds[MT * 136];
    __shared__ float priv[256 * HSTRIDE];   // per-thread 26-bin hist, stride 27
    __shared__ float posh[QT * NBIN];       // shared positives hist (sparse atomics)

    int tid  = threadIdx.x;
    int bidx = blockIdx.x;
    int b      = bidx / (NTILES * MSPLIT);
    int rem    = bidx % (NTILES * MSPLIT);
    int ntile  = rem / MSPLIT;
    int msplit = rem % MSPLIT;
    int n0 = ntile * QT;

    for (int i = tid; i < 256 * HSTRIDE; i += 256) priv[i] = 0.0f;
    for (int i = tid; i < QT * NBIN; i += 256) posh[i] = 0.0f;
    {   // load Q tile: 16 rows x 128 bf16
        int row = tid >> 4, col = tid & 15;
        *reinterpret_cast<uint4*>(&Qs[row * 136 + col * 8]) =
            *reinterpret_cast<const uint4*>(Qt + ((size_t)(b * NN + n0 + row)) * CC + col * 8);
    }
    int lane = tid & 63, wave = tid >> 6, quad = lane >> 4, l15 = lane & 15;
    int q  = l15;                 // this lane's query for the WHOLE kernel
    int n  = n0 + q;
    int rn = n / WW, cn = n % WW;
    float* ph = &priv[tid * HSTRIDE];

    int mstart = msplit * (NN / MSPLIT);
    for (int it = 0; it < ITERS; ++it) {
        int m0 = mstart + it * MT;
        __syncthreads();
        #pragma unroll
        for (int k = 0; k < 4; ++k) {
            int idx = tid + k * 256;
            int row = idx >> 4, col = idx & 15;
            *reinterpret_cast<uint4*>(&Ds[row * 136 + col * 8]) =
                *reinterpret_cast<const uint4*>(Dt + ((size_t)(b * NN + m0 + row)) * CC + col * 8);
        }
        __syncthreads();

        f32x4 acc = {0.f, 0.f, 0.f, 0.f};
        #pragma unroll
        for (int kc = 0; kc < 4; ++kc) {
            // A = D rows (M dim = m), B = Q rows (N dim = q)  ->  C[m][q]
            bf16x8 av = *reinterpret_cast<const bf16x8*>(&Ds[(wave * 16 + l15) * 136 + kc * 32 + quad * 8]);
            bf16x8 bv = *reinterpret_cast<const bf16x8*>(&Qs[l15 * 136 + kc * 32 + quad * 8]);
            acc = __builtin_amdgcn_mfma_f32_16x16x32_bf16(av, bv, acc, 0, 0, 0);
        }

        int mb = m0 + wave * 16 + quad * 4;   // C row = quad*4+i (m), col = l15 (q)
        #pragma unroll
        for (int i = 0; i < 4; ++i) {
            float s  = acc[i];
            float t  = fminf(fmaxf(12.0f - 12.0f * s, 0.0f), 24.0f);
            float cf = floorf(t);
            float f  = t - cf;
            int   c0 = (int)cf;               // [0,24]; c0==24 -> f==0 -> spill bin +0
            float h0 = ph[c0], h1 = ph[c0 + 1];
            ph[c0]     = h0 + (1.0f - f);
            ph[c0 + 1] = h1 + f;
            int m  = mb + i;
            int rm = m / WW, cm = m - rm * WW;
            int dr = rn - rm, dc = cn - cm;
            if ((unsigned)(dr + 4) <= 8u && (unsigned)(dc + 4) <= 8u) {
                atomicAdd(&posh[q * NBIN + c0],     1.0f - f);
                atomicAdd(&posh[q * NBIN + c0 + 1], f);
            }
        }
    }
    __syncthreads();
    // reduce 16 private hists per query, flush with 4-way-contended global atomics
    for (int idx = tid; idx < QT * NBIN; idx += 256) {
        int qq = idx / NBIN, c = idx % NBIN;
        float s = 0.0f;
        #pragma unroll
        for (int j = 0; j < 16; ++j) s += priv[(j * 16 + qq) * HSTRIDE + c];
        size_t g = ((size_t)(b * NN + n0 + qq)) * NBIN + c;
        atomicAdd(&Hall[g], s);
        atomicAdd(&Hpos[g], posh[idx]);
    }
}

// AP from histograms + reliability + mean -> scalar
__global__ void k_finalize(const float* __restrict__ Hall, const float* __restrict__ Hpos,
                           const float* __restrict__ rel, float* __restrict__ out) {
    int gid = blockIdx.x * 256 + threadIdx.x;   // 0..4607
    const float* ha = Hall + (size_t)gid * NBIN;
    const float* hp = Hpos + (size_t)gid * NBIN;
    float cumr = 0.f, cumn = 0.f, apn = 0.f, totr = 0.f;
    #pragma unroll
    for (int c2 = 0; c2 < 25; ++c2) {
        float r = hp[c2], a = ha[c2];
        cumr += r; cumn += a;
        apn  += (cumr / (1e-16f + cumn)) * r;
        totr += r;
    }
    float ap = apn / totr;
    float rl = rel[gid];
    float loss = 1.0f - (ap * rl + 0.5f * (1.0f - rl));

    for (int off = 32; off > 0; off >>= 1) loss += __shfl_down(loss, off, 64);
    __shared__ float wsum[4];
    int ln = threadIdx.x & 63, wv = threadIdx.x >> 6;
    if (ln == 0) wsum[wv] = loss;
    __syncthreads();
    if (threadIdx.x == 0) {
        float t = wsum[0] + wsum[1] + wsum[2] + wsum[3];
        atomicAdd(out, t * (1.0f / (float)(BB * NN)));
    }
}

extern "C" void kernel_launch(void* const* d_in, const int* in_sizes, int n_in,
                              void* d_out, int out_size, void* d_ws, size_t ws_size,
                              hipStream_t stream) {
    const float* img1 = (const float*)d_in[0];
    const float* img2 = (const float*)d_in[1];
    const float* rel  = (const float*)d_in[2];
    const float* grid = (const float*)d_in[3];

    char* ws = (char*)d_ws;
    const size_t qt_bytes   = (size_t)BB * NN * CC * sizeof(u16);      // 1.18 MB
    const size_t hist_bytes = (size_t)BB * NN * NBIN * sizeof(float);  // 479 KB
    u16*   Qt   = (u16*)ws;
    u16*   Dt   = (u16*)(ws + qt_bytes);
    float* Hall = (float*)(ws + 2 * qt_bytes);
    float* Hpos = (float*)(ws + 2 * qt_bytes + hist_bytes);

    hipMemsetAsync(d_out, 0, sizeof(float), stream);
    hipMemsetAsync(Hall, 0, 2 * hist_bytes, stream);

    k_transpose <<<(BB * CC * NN) / 256, 256, 0, stream>>>(img1, Qt);
    k_gridsample<<<(BB * NN / 256) * CSPLIT, 256, 0, stream>>>(img2, grid, Dt);
    k_main      <<<BB * NTILES * MSPLIT, 256, 0, stream>>>(Qt, Dt, Hall, Hpos);
    k_finalize  <<<(BB * NN) / 256, 256, 0, stream>>>(Hall, Hpos, rel, (float*)d_out);
}